// Round 4
// baseline (9387.648 us; speedup 1.0000x reference)
//
#include <hip/hip_runtime.h>
#include <stdint.h>

#define B_   64
#define T_   512
#define EI_  1024
#define EO_  1024

typedef __attribute__((ext_vector_type(4))) float  f32x4;
typedef __attribute__((ext_vector_type(8))) short  s16x8;
typedef __attribute__((ext_vector_type(4))) unsigned short u16x4;
typedef unsigned long long u64;

__device__ __forceinline__ unsigned short f2bf(float f) {
    union { float f; unsigned int u; } v; v.f = f;
    unsigned int r = v.u + 0x7FFFu + ((v.u >> 16) & 1u);
    return (unsigned short)(r >> 16);
}

// ---- prep: LDS tile-transpose weights to bf16 [N][K]; init versioned H buffer parity-1 (ver=0) ----
__global__ void prep_kernel(const float* __restrict__ wxh, const float* __restrict__ whf,
                            const float* __restrict__ h0,
                            unsigned short* __restrict__ wxhT, unsigned short* __restrict__ whfT,
                            u64* __restrict__ hv)          // [2][64][512] u64 = [ver32|bf16x2]
{
    __shared__ unsigned short Ts[64][72];
    const int bid = blockIdx.x;
    const float* src = (bid & 1) ? whf : wxh;
    unsigned short* dst = (bid & 1) ? whfT : wxhT;
    const int tile = bid >> 1;                  // 0..255
    const int k0 = (tile >> 4) * 64, n0 = (tile & 15) * 64;
    const int tid = threadIdx.x;

    #pragma unroll
    for (int it = 0; it < 4; ++it) {            // read 64x64 f32, coalesced rows
        int r  = it * 16 + (tid >> 4);
        int cq = tid & 15;
        f32x4 v = *(const f32x4*)(src + (size_t)(k0 + r) * EO_ + n0 + cq * 4);
        #pragma unroll
        for (int i = 0; i < 4; ++i) Ts[cq * 4 + i][r] = f2bf(v[i]);
    }
    __syncthreads();
    #pragma unroll
    for (int it = 0; it < 2; ++it) {            // write transposed, coalesced 16B rows
        int n = it * 32 + (tid >> 3);
        int c = tid & 7;
        s16x8 v = *(const s16x8*)(&Ts[n][c * 8]);
        *(s16x8*)(dst + (size_t)(n0 + n) * EI_ + k0 + c * 8) = v;
    }
    if (bid < 128) {                            // h0 -> versioned parity-1 buffer, ver=0
        int idx = bid * 256 + tid;              // 0..32767 == r*512 + c2
        int r = idx >> 9, c2 = idx & 511;
        unsigned int pay = (unsigned int)f2bf(h0[(size_t)r * EO_ + c2 * 2])
                         | ((unsigned int)f2bf(h0[(size_t)r * EO_ + c2 * 2 + 1]) << 16);
        hv[32768 + idx] = ((u64)pay << 32);     // ver = 0
    }
}

// ---- kernel 1: G = tanh(X @ wxh) into the outs region of d_out (unchanged, proven) ----
__launch_bounds__(256, 2)
__global__ void gemm_g_kernel(const float* __restrict__ X,
                              const unsigned short* __restrict__ WT,
                              float* __restrict__ out)
{
    __shared__ alignas(16) unsigned short As[128 * 72];
    __shared__ alignas(16) unsigned short Bs[128 * 72];

    const int bid = blockIdx.x;
    const int bn = bid & 7, bm = bid >> 3;
    const int m0 = bm * 128, n0 = bn * 128;
    const int tid  = threadIdx.x;
    const int lane = tid & 63, w = tid >> 6;
    const int wr = w >> 1, wc = w & 1;
    const int l15 = lane & 15, lg = lane >> 4;

    f32x4 acc[4][4] = {};

    for (int kt = 0; kt < EI_ / 64; ++kt) {
        const int k0 = kt * 64;
        #pragma unroll
        for (int p = 0; p < 8; ++p) {
            int row = p * 16 + (tid >> 4);
            int kq  = tid & 15;
            f32x4 v = *(const f32x4*)(X + (size_t)(m0 + row) * EI_ + k0 + kq * 4);
            u16x4 hv4;
            hv4[0] = f2bf(v[0]); hv4[1] = f2bf(v[1]); hv4[2] = f2bf(v[2]); hv4[3] = f2bf(v[3]);
            *(u16x4*)(&As[row * 72 + kq * 4]) = hv4;
        }
        #pragma unroll
        for (int p = 0; p < 4; ++p) {
            int n  = p * 32 + (tid >> 3);
            int kq = tid & 7;
            s16x8 v = *(const s16x8*)(WT + (size_t)(n0 + n) * EI_ + k0 + kq * 8);
            *(s16x8*)(&Bs[n * 72 + kq * 8]) = v;
        }
        __syncthreads();
        #pragma unroll
        for (int kk = 0; kk < 2; ++kk) {
            s16x8 a[4], b[4];
            #pragma unroll
            for (int mt = 0; mt < 4; ++mt)
                a[mt] = *(const s16x8*)(&As[(wr * 64 + mt * 16 + l15) * 72 + kk * 32 + lg * 8]);
            #pragma unroll
            for (int nt = 0; nt < 4; ++nt)
                b[nt] = *(const s16x8*)(&Bs[(wc * 64 + nt * 16 + l15) * 72 + kk * 32 + lg * 8]);
            #pragma unroll
            for (int mt = 0; mt < 4; ++mt)
                #pragma unroll
                for (int nt = 0; nt < 4; ++nt)
                    acc[mt][nt] = __builtin_amdgcn_mfma_f32_16x16x32_bf16(a[mt], b[nt], acc[mt][nt], 0, 0, 0);
        }
        __syncthreads();
    }
    #pragma unroll
    for (int mt = 0; mt < 4; ++mt) {
        #pragma unroll
        for (int nt = 0; nt < 4; ++nt) {
            #pragma unroll
            for (int r = 0; r < 4; ++r) {
                int row = wr * 64 + mt * 16 + lg * 4 + r;
                int col = wc * 64 + nt * 16 + l15;
                float s = acc[mt][nt][r];
                float e = __expf(2.f * s);
                out[(size_t)(m0 + row) * EO_ + n0 + col] = 1.f - 2.f / (e + 1.f);
            }
        }
    }
}

// ---- kernel 2: recurrence, versioned-payload dataflow (NO flags, NO fences, NO drains).
// 64 blocks x 256 thr = 4 batch-groups x 16 col-blocks; wave = 16 cols, W in forced registers.
// Block cooperatively fills XOR-swizzled LDS H-tile from versioned u64s, retrying stale words.
__launch_bounds__(256, 1)
__global__ void recur_kernel(const float* __restrict__ h0,
                             const unsigned short* __restrict__ whfT, // whf^T bf16 [N][K]
                             u64* hv,                                 // [2][64][512] versioned
                             float* out)
{
    __shared__ alignas(16) unsigned short Hs[2][16 * 1024];   // 2 x 32KB, XOR-swizzled

    const int bid = blockIdx.x;          // 0..63
    const int g = bid >> 4;              // batch group 0..3
    const int cblk = bid & 15;           // col block 0..15
    const int tid = threadIdx.x;
    const int lane = tid & 63, w = tid >> 6;
    const int l15 = lane & 15, lg = lane >> 4;
    const int colbase = (cblk * 4 + w) * 16;
    const int col = colbase + l15;
    const int rowbase = g * 16 + lg * 4;

    // whf columns resident in registers: 32 frags x 4 VGPR = 128 VGPR, forced via opaque asm def
    f32x4 WfF[32];
    #pragma unroll
    for (int kk = 0; kk < 32; ++kk)
        WfF[kk] = *(const f32x4*)(whfT + (size_t)col * EO_ + kk * 32 + lg * 8);
    #pragma unroll
    for (int kk = 0; kk < 32; ++kk)
        asm volatile("" : "+v"(WfF[kk]));

    float h[4];
    #pragma unroll
    for (int r = 0; r < 4; ++r)
        h[r] = h0[(size_t)(rowbase + r) * EO_ + col];

    for (int t = 0; t < T_; ++t) {
        // prefetch g_t (no cross-block dependence) to hide HBM latency under the fill
        float gv[4];
        #pragma unroll
        for (int r = 0; r < 4; ++r)
            gv[r] = out[((size_t)(rowbase + r) * T_ + t) * EO_ + col];

        // ---- fill phase: LDS[t&1] <- group H_{t-1} from hv[(t&1)^1], want ver == t ----
        char* HsW = (char*)&Hs[t & 1][0];
        const u64* src = hv + (size_t)((t & 1) ^ 1) * 32768 + (size_t)g * 8192;
        const unsigned int want = (unsigned int)t;

        u64 v0[16], v1[16];
        #pragma unroll
        for (int i = 0; i < 16; ++i) {          // bulk issue: all 32 loads in flight
            int pi = i * 256 + tid;
            int base = (pi >> 8) * 512 + (pi & 255) * 2;
            v0[i] = __hip_atomic_load(&src[base],     __ATOMIC_RELAXED, __HIP_MEMORY_SCOPE_AGENT);
            v1[i] = __hip_atomic_load(&src[base + 1], __ATOMIC_RELAXED, __HIP_MEMORY_SCOPE_AGENT);
        }
        unsigned int done = 0;
        for (int pass = 0; done != 0xFFFFu && pass < (1 << 14); ++pass) {
            #pragma unroll
            for (int i = 0; i < 16; ++i) {
                if (!(done & (1u << i))) {
                    if ((unsigned int)v0[i] == want && (unsigned int)v1[i] == want) {
                        int pi = i * 256 + tid;
                        int r = pi >> 8, p255 = pi & 255;
                        u64 pay = (v0[i] >> 32) | ((v1[i] >> 32) << 32);
                        int off = (r * 2048 + p255 * 8) ^ ((r & 7) << 4);
                        *(u64*)(HsW + off) = pay;
                        done |= 1u << i;
                    } else {
                        int pi = i * 256 + tid;
                        int base = (pi >> 8) * 512 + (pi & 255) * 2;
                        v0[i] = __hip_atomic_load(&src[base],     __ATOMIC_RELAXED, __HIP_MEMORY_SCOPE_AGENT);
                        v1[i] = __hip_atomic_load(&src[base + 1], __ATOMIC_RELAXED, __HIP_MEMORY_SCOPE_AGENT);
                    }
                }
            }
        }
        __syncthreads();

        // ---- consume phase: 32 MFMA, A from swizzled LDS, B from resident registers ----
        const char* HsR = (const char*)&Hs[t & 1][0];
        f32x4 acc[4] = {};
        #pragma unroll
        for (int kk = 0; kk < 32; ++kk) {
            int off = (l15 * 2048 + kk * 64 + lg * 16) ^ ((l15 & 7) << 4);
            s16x8 a = *(const s16x8*)(HsR + off);
            union { f32x4 f; s16x8 s; } wf; wf.f = WfF[kk];
            acc[kk & 3] = __builtin_amdgcn_mfma_f32_16x16x32_bf16(a, wf.s, acc[kk & 3], 0, 0, 0);
        }

        unsigned short hb[4];
        #pragma unroll
        for (int r = 0; r < 4; ++r) {
            float s = acc[0][r] + acc[1][r] + acc[2][r] + acc[3][r];
            float fg = 1.f / (1.f + __expf(-s));
            h[r] = (1.f - fg) * h[r] + fg * gv[r];
            out[((size_t)(rowbase + r) * T_ + t) * EO_ + col] = h[r];
            hb[r] = f2bf(h[r]);
        }

        // ---- versioned store of H_t into hv[t&1], ver = t+1 (single atomic u64 per col-pair) ----
        u64* dst = hv + (size_t)(t & 1) * 32768 + (size_t)g * 8192;
        #pragma unroll
        for (int r = 0; r < 4; ++r) {
            unsigned int other = (unsigned int)__shfl_xor((int)(unsigned int)hb[r], 1);
            if (!(lane & 1)) {
                unsigned int pay = (unsigned int)hb[r] | (other << 16);
                u64 vv = (u64)(unsigned int)(t + 1) | ((u64)pay << 32);
                __hip_atomic_store(&dst[(lg * 4 + r) * 512 + ((colbase + l15) >> 1)],
                                   vv, __ATOMIC_RELAXED, __HIP_MEMORY_SCOPE_AGENT);
            }
        }
        // no drain, no flag: the version tag carries the synchronization
    }
    #pragma unroll
    for (int r = 0; r < 4; ++r)
        out[(size_t)B_ * T_ * EO_ + (size_t)(rowbase + r) * EO_ + col] = h[r];
}

extern "C" void kernel_launch(void* const* d_in, const int* in_sizes, int n_in,
                              void* d_out, int out_size, void* d_ws, size_t ws_size,
                              hipStream_t stream)
{
    const float* x   = (const float*)d_in[0];
    const float* h0  = (const float*)d_in[1];
    const float* wxh = (const float*)d_in[2];
    const float* whf = (const float*)d_in[3];
    float* out = (float*)d_out;

    char* ws = (char*)d_ws;
    unsigned short* whfT = (unsigned short*)(ws);
    unsigned short* wxhT = (unsigned short*)(ws + (size_t)2 * 1024 * 1024);
    u64*            hv   = (u64*)           (ws + (size_t)4 * 1024 * 1024);  // 2*64*512*8 = 512KB

    prep_kernel<<<512, 256, 0, stream>>>(wxh, whf, h0, wxhT, whfT, hv);
    gemm_g_kernel<<<2048, 256, 0, stream>>>(x, wxhT, out);
    recur_kernel<<<64, 256, 0, stream>>>(h0, whfT, hv, out);
}

// Round 5
// 5595.314 us; speedup vs baseline: 1.6778x; 1.6778x over previous
//
#include <hip/hip_runtime.h>
#include <stdint.h>

#define B_   64
#define T_   512
#define EI_  1024
#define EO_  1024

typedef __attribute__((ext_vector_type(4))) float  f32x4;
typedef __attribute__((ext_vector_type(8))) short  s16x8;
typedef __attribute__((ext_vector_type(4))) unsigned short u16x4;
typedef unsigned long long u64;

__device__ __forceinline__ unsigned short f2bf(float f) {
    union { float f; unsigned int u; } v; v.f = f;
    unsigned int r = v.u + 0x7FFFu + ((v.u >> 16) & 1u);
    return (unsigned short)(r >> 16);
}

// ---- prep: LDS tile-transpose weights to bf16 [N][K]; init H parity-1 = bf16(h0); zero flags ----
__global__ void prep_kernel(const float* __restrict__ wxh, const float* __restrict__ whf,
                            const float* __restrict__ h0,
                            unsigned short* __restrict__ wxhT, unsigned short* __restrict__ whfT,
                            unsigned short* __restrict__ hbf,   // [2][4][16][1024] bf16
                            unsigned int* __restrict__ flags)   // [4][64]
{
    __shared__ unsigned short Ts[64][72];
    const int bid = blockIdx.x;
    const float* src = (bid & 1) ? whf : wxh;
    unsigned short* dst = (bid & 1) ? whfT : wxhT;
    const int tile = bid >> 1;                  // 0..255
    const int k0 = (tile >> 4) * 64, n0 = (tile & 15) * 64;
    const int tid = threadIdx.x;

    #pragma unroll
    for (int it = 0; it < 4; ++it) {            // read 64x64 f32, coalesced rows
        int r  = it * 16 + (tid >> 4);
        int cq = tid & 15;
        f32x4 v = *(const f32x4*)(src + (size_t)(k0 + r) * EO_ + n0 + cq * 4);
        #pragma unroll
        for (int i = 0; i < 4; ++i) Ts[cq * 4 + i][r] = f2bf(v[i]);
    }
    __syncthreads();
    #pragma unroll
    for (int it = 0; it < 2; ++it) {            // write transposed, coalesced 16B rows
        int n = it * 32 + (tid >> 3);
        int c = tid & 7;
        s16x8 v = *(const s16x8*)(&Ts[n][c * 8]);
        *(s16x8*)(dst + (size_t)(n0 + n) * EI_ + k0 + c * 8) = v;
    }
    if (bid < 256) {                            // h0 -> bf16 parity-1 buffer (linear layout match)
        int idx = bid * 256 + tid;              // 0..65535 == b*1024 + col
        hbf[65536 + idx] = f2bf(h0[idx]);
    }
    if (bid == 0) flags[tid] = 0u;              // zero all 4*64 flags (replay-safe)
}

// ---- kernel 1: G = tanh(X @ wxh) into the outs region of d_out (unchanged, proven) ----
__launch_bounds__(256, 2)
__global__ void gemm_g_kernel(const float* __restrict__ X,
                              const unsigned short* __restrict__ WT,
                              float* __restrict__ out)
{
    __shared__ alignas(16) unsigned short As[128 * 72];
    __shared__ alignas(16) unsigned short Bs[128 * 72];

    const int bid = blockIdx.x;
    const int bn = bid & 7, bm = bid >> 3;
    const int m0 = bm * 128, n0 = bn * 128;
    const int tid  = threadIdx.x;
    const int lane = tid & 63, w = tid >> 6;
    const int wr = w >> 1, wc = w & 1;
    const int l15 = lane & 15, lg = lane >> 4;

    f32x4 acc[4][4] = {};

    for (int kt = 0; kt < EI_ / 64; ++kt) {
        const int k0 = kt * 64;
        #pragma unroll
        for (int p = 0; p < 8; ++p) {
            int row = p * 16 + (tid >> 4);
            int kq  = tid & 15;
            f32x4 v = *(const f32x4*)(X + (size_t)(m0 + row) * EI_ + k0 + kq * 4);
            u16x4 hv4;
            hv4[0] = f2bf(v[0]); hv4[1] = f2bf(v[1]); hv4[2] = f2bf(v[2]); hv4[3] = f2bf(v[3]);
            *(u16x4*)(&As[row * 72 + kq * 4]) = hv4;
        }
        #pragma unroll
        for (int p = 0; p < 4; ++p) {
            int n  = p * 32 + (tid >> 3);
            int kq = tid & 7;
            s16x8 v = *(const s16x8*)(WT + (size_t)(n0 + n) * EI_ + k0 + kq * 8);
            *(s16x8*)(&Bs[n * 72 + kq * 8]) = v;
        }
        __syncthreads();
        #pragma unroll
        for (int kk = 0; kk < 2; ++kk) {
            s16x8 a[4], b[4];
            #pragma unroll
            for (int mt = 0; mt < 4; ++mt)
                a[mt] = *(const s16x8*)(&As[(wr * 64 + mt * 16 + l15) * 72 + kk * 32 + lg * 8]);
            #pragma unroll
            for (int nt = 0; nt < 4; ++nt)
                b[nt] = *(const s16x8*)(&Bs[(wc * 64 + nt * 16 + l15) * 72 + kk * 32 + lg * 8]);
            #pragma unroll
            for (int mt = 0; mt < 4; ++mt)
                #pragma unroll
                for (int nt = 0; nt < 4; ++nt)
                    acc[mt][nt] = __builtin_amdgcn_mfma_f32_16x16x32_bf16(a[mt], b[nt], acc[mt][nt], 0, 0, 0);
        }
        __syncthreads();
    }
    #pragma unroll
    for (int mt = 0; mt < 4; ++mt) {
        #pragma unroll
        for (int nt = 0; nt < 4; ++nt) {
            #pragma unroll
            for (int r = 0; r < 4; ++r) {
                int row = wr * 64 + mt * 16 + lg * 4 + r;
                int col = wc * 64 + nt * 16 + l15;
                float s = acc[mt][nt][r];
                float e = __expf(2.f * s);
                out[(size_t)(m0 + row) * EO_ + n0 + col] = 1.f - 2.f / (e + 1.f);
            }
        }
    }
}

// ---- kernel 2: recurrence, wave-autonomous, ZERO barriers in the loop.
// 64 blocks x 4 waves. Block j owns cols [16j,16j+16) (W slice in LDS, padded stride).
// Wave g owns batch group g: independent 512-step loop. Swapped MFMA (A=W, B=H):
// lane holds (batch row = lane&15, 4 contiguous cols = (lane>>4)*4+r) -> all I/O is
// one 16B/8B op per lane. Flags: 64 lanes poll 64 producer blocks with ONE load.
__launch_bounds__(256, 1)
__global__ void recur_kernel(const float* __restrict__ h0,
                             const unsigned short* __restrict__ whfT, // whf^T bf16 [N][K]
                             unsigned short* hbf,                     // [2][4][16][1024] bf16
                             unsigned int* flags,                     // [4][64]
                             float* out)
{
    __shared__ alignas(16) unsigned short Ws[16 * 1032];   // 16 cols x 1024 k, stride 1032

    const int j = blockIdx.x;            // col block 0..63
    const int tid = threadIdx.x;
    const int lane = tid & 63;
    const int g = tid >> 6;              // wave = batch group 0..3
    const int l15 = lane & 15, lg = lane >> 4;

    // cooperative one-time W fill (padded stride: conflict-optimal 8-beat ds_read_b128)
    {
        int c = tid >> 4, k8 = tid & 15;
        #pragma unroll
        for (int p = 0; p < 8; ++p) {
            int k = (k8 + p * 16) * 8;
            s16x8 v = *(const s16x8*)(whfT + (size_t)(j * 16 + c) * EO_ + k);
            *(s16x8*)(&Ws[c * 1032 + k]) = v;
        }
    }
    __syncthreads();                      // only barrier in the kernel

    const int row = g * 16 + l15;         // batch row this lane produces
    const int c0  = j * 16 + lg * 4;      // first of this lane's 4 output cols
    float h[4];
    {
        f32x4 v = *(const f32x4*)(h0 + (size_t)row * EO_ + c0);
        h[0] = v[0]; h[1] = v[1]; h[2] = v[2]; h[3] = v[3];
    }
    unsigned int* const flg = flags + g * 64;

    for (int t = 0; t < T_; ++t) {
        // g_t prefetch: block-local cols of out (written by gemm kernel; no cross-block alias)
        f32x4 gv = *(const f32x4*)(out + ((size_t)row * T_ + t) * EO_ + c0);

        // poll: lane l watches producer block l of this group (t=0 passes trivially)
        const unsigned int want = (unsigned int)t;
        int spins = 0;
        for (;;) {
            unsigned int f = __hip_atomic_load(&flg[lane], __ATOMIC_RELAXED,
                                               __HIP_MEMORY_SCOPE_AGENT);
            if (__ballot(f >= want) == ~0ULL) break;
            if (++spins > (1 << 20)) break;          // safety valve
        }
        asm volatile("" ::: "memory");               // no compile-time hoist of A-loads

        // A = H_{t-1}[g], row l15, full K=1024: 64 coherent u64 loads, all in flight
        const unsigned short* arow = hbf + (size_t)((t & 1) ^ 1) * 65536
                                   + (size_t)g * 16384 + (size_t)l15 * 1024;
        u64 a0[32], a1[32];
        #pragma unroll
        for (int kk = 0; kk < 32; ++kk) {
            a0[kk] = __hip_atomic_load((const u64*)(arow + kk * 32 + lg * 8),
                                       __ATOMIC_RELAXED, __HIP_MEMORY_SCOPE_AGENT);
            a1[kk] = __hip_atomic_load((const u64*)(arow + kk * 32 + lg * 8 + 4),
                                       __ATOMIC_RELAXED, __HIP_MEMORY_SCOPE_AGENT);
        }
        f32x4 acc[4] = {};
        #pragma unroll
        for (int kk = 0; kk < 32; ++kk) {
            s16x8 wfrag = *(const s16x8*)(&Ws[l15 * 1032 + kk * 32 + lg * 8]);
            union { u64 u[2]; s16x8 v; } av;
            av.u[0] = a0[kk]; av.u[1] = a1[kk];
            // A = W (m = W-col), B = H (n = batch row): D lane&15 = row, regs = 4 cols
            acc[kk & 3] = __builtin_amdgcn_mfma_f32_16x16x32_bf16(wfrag, av.v, acc[kk & 3], 0, 0, 0);
        }

        f32x4 ho;
        #pragma unroll
        for (int r = 0; r < 4; ++r) {
            float s = acc[0][r] + acc[1][r] + acc[2][r] + acc[3][r];
            float fg = 1.f / (1.f + __expf(-s));
            h[r] = (1.f - fg) * h[r] + fg * gv[r];
            ho[r] = h[r];
        }
        *(f32x4*)(out + ((size_t)row * T_ + t) * EO_ + c0) = ho;   // h_t -> outs (plain)

        // packed bf16 H-store: one coherent u64 per lane
        u64 pk = (u64)f2bf(h[0]) | ((u64)f2bf(h[1]) << 16)
               | ((u64)f2bf(h[2]) << 32) | ((u64)f2bf(h[3]) << 48);
        __hip_atomic_store((u64*)(hbf + (size_t)(t & 1) * 65536 + (size_t)g * 16384
                                  + (size_t)l15 * 1024 + c0 - j * 16 + j * 16),  // = ... + l15*1024 + c0
                           pk, __ATOMIC_RELAXED, __HIP_MEMORY_SCOPE_AGENT);

        asm volatile("s_waitcnt vmcnt(0)" ::: "memory");   // drain H-store before flag
        if (lane == 0)
            __hip_atomic_store(&flg[j], (unsigned int)(t + 1),
                               __ATOMIC_RELAXED, __HIP_MEMORY_SCOPE_AGENT);
    }

    // final hidden state hT
    f32x4 hf; hf[0] = h[0]; hf[1] = h[1]; hf[2] = h[2]; hf[3] = h[3];
    *(f32x4*)(out + (size_t)B_ * T_ * EO_ + (size_t)row * EO_ + c0) = hf;
}

extern "C" void kernel_launch(void* const* d_in, const int* in_sizes, int n_in,
                              void* d_out, int out_size, void* d_ws, size_t ws_size,
                              hipStream_t stream)
{
    const float* x   = (const float*)d_in[0];
    const float* h0  = (const float*)d_in[1];
    const float* wxh = (const float*)d_in[2];
    const float* whf = (const float*)d_in[3];
    float* out = (float*)d_out;

    char* ws = (char*)d_ws;
    unsigned short* whfT  = (unsigned short*)(ws);                               // 2MB
    unsigned short* wxhT  = (unsigned short*)(ws + (size_t)2 * 1024 * 1024);     // 2MB
    unsigned short* hbf   = (unsigned short*)(ws + (size_t)4 * 1024 * 1024);     // 256KB
    unsigned int*   flags = (unsigned int*)  (ws + (size_t)4 * 1024 * 1024 + 256 * 1024);

    prep_kernel<<<512, 256, 0, stream>>>(wxh, whf, h0, wxhT, whfT, hbf, flags);
    gemm_g_kernel<<<2048, 256, 0, stream>>>(x, wxhT, out);
    recur_kernel<<<64, 256, 0, stream>>>(h0, whfT, hbf, flags, out);
}

// Round 6
// 4089.537 us; speedup vs baseline: 2.2955x; 1.3682x over previous
//
#include <hip/hip_runtime.h>
#include <stdint.h>

#define B_   64
#define T_   512
#define EI_  1024
#define EO_  1024

typedef __attribute__((ext_vector_type(4))) float  f32x4;
typedef __attribute__((ext_vector_type(8))) short  s16x8;
typedef __attribute__((ext_vector_type(4))) unsigned short u16x4;
typedef unsigned long long u64;

__device__ __forceinline__ unsigned short f2bf(float f) {
    union { float f; unsigned int u; } v; v.f = f;
    unsigned int r = v.u + 0x7FFFu + ((v.u >> 16) & 1u);
    return (unsigned short)(r >> 16);
}

// ---- prep: LDS tile-transpose weights to bf16 [N][K]; init H parity-1 = bf16(h0); zero flags ----
__global__ void prep_kernel(const float* __restrict__ wxh, const float* __restrict__ whf,
                            const float* __restrict__ h0,
                            unsigned short* __restrict__ wxhT, unsigned short* __restrict__ whfT,
                            unsigned short* __restrict__ hbf,   // [2][64][1024] bf16
                            unsigned int* __restrict__ flags)   // [4][64]
{
    __shared__ unsigned short Ts[64][72];
    const int bid = blockIdx.x;
    const float* src = (bid & 1) ? whf : wxh;
    unsigned short* dst = (bid & 1) ? whfT : wxhT;
    const int tile = bid >> 1;                  // 0..255
    const int k0 = (tile >> 4) * 64, n0 = (tile & 15) * 64;
    const int tid = threadIdx.x;

    #pragma unroll
    for (int it = 0; it < 4; ++it) {            // read 64x64 f32, coalesced rows
        int r  = it * 16 + (tid >> 4);
        int cq = tid & 15;
        f32x4 v = *(const f32x4*)(src + (size_t)(k0 + r) * EO_ + n0 + cq * 4);
        #pragma unroll
        for (int i = 0; i < 4; ++i) Ts[cq * 4 + i][r] = f2bf(v[i]);
    }
    __syncthreads();
    #pragma unroll
    for (int it = 0; it < 2; ++it) {            // write transposed, coalesced 16B rows
        int n = it * 32 + (tid >> 3);
        int c = tid & 7;
        s16x8 v = *(const s16x8*)(&Ts[n][c * 8]);
        *(s16x8*)(dst + (size_t)(n0 + n) * EI_ + k0 + c * 8) = v;
    }
    if (bid < 256) {                            // h0 -> bf16 parity-1 buffer (linear layout)
        int idx = bid * 256 + tid;              // 0..65535 == b*1024 + col
        hbf[65536 + idx] = f2bf(h0[idx]);
    }
    if (bid == 0) flags[tid] = 0u;              // zero all 4*64 flags (replay-safe)
}

// ---- kernel 1: G = tanh(X @ wxh) into the outs region of d_out (unchanged, proven) ----
__launch_bounds__(256, 2)
__global__ void gemm_g_kernel(const float* __restrict__ X,
                              const unsigned short* __restrict__ WT,
                              float* __restrict__ out)
{
    __shared__ alignas(16) unsigned short As[128 * 72];
    __shared__ alignas(16) unsigned short Bs[128 * 72];

    const int bid = blockIdx.x;
    const int bn = bid & 7, bm = bid >> 3;
    const int m0 = bm * 128, n0 = bn * 128;
    const int tid  = threadIdx.x;
    const int lane = tid & 63, w = tid >> 6;
    const int wr = w >> 1, wc = w & 1;
    const int l15 = lane & 15, lg = lane >> 4;

    f32x4 acc[4][4] = {};

    for (int kt = 0; kt < EI_ / 64; ++kt) {
        const int k0 = kt * 64;
        #pragma unroll
        for (int p = 0; p < 8; ++p) {
            int row = p * 16 + (tid >> 4);
            int kq  = tid & 15;
            f32x4 v = *(const f32x4*)(X + (size_t)(m0 + row) * EI_ + k0 + kq * 4);
            u16x4 hv4;
            hv4[0] = f2bf(v[0]); hv4[1] = f2bf(v[1]); hv4[2] = f2bf(v[2]); hv4[3] = f2bf(v[3]);
            *(u16x4*)(&As[row * 72 + kq * 4]) = hv4;
        }
        #pragma unroll
        for (int p = 0; p < 4; ++p) {
            int n  = p * 32 + (tid >> 3);
            int kq = tid & 7;
            s16x8 v = *(const s16x8*)(WT + (size_t)(n0 + n) * EI_ + k0 + kq * 8);
            *(s16x8*)(&Bs[n * 72 + kq * 8]) = v;
        }
        __syncthreads();
        #pragma unroll
        for (int kk = 0; kk < 2; ++kk) {
            s16x8 a[4], b[4];
            #pragma unroll
            for (int mt = 0; mt < 4; ++mt)
                a[mt] = *(const s16x8*)(&As[(wr * 64 + mt * 16 + l15) * 72 + kk * 32 + lg * 8]);
            #pragma unroll
            for (int nt = 0; nt < 4; ++nt)
                b[nt] = *(const s16x8*)(&Bs[(wc * 64 + nt * 16 + l15) * 72 + kk * 32 + lg * 8]);
            #pragma unroll
            for (int mt = 0; mt < 4; ++mt)
                #pragma unroll
                for (int nt = 0; nt < 4; ++nt)
                    acc[mt][nt] = __builtin_amdgcn_mfma_f32_16x16x32_bf16(a[mt], b[nt], acc[mt][nt], 0, 0, 0);
        }
        __syncthreads();
    }
    #pragma unroll
    for (int mt = 0; mt < 4; ++mt) {
        #pragma unroll
        for (int nt = 0; nt < 4; ++nt) {
            #pragma unroll
            for (int r = 0; r < 4; ++r) {
                int row = wr * 64 + mt * 16 + lg * 4 + r;
                int col = wc * 64 + nt * 16 + l15;
                float s = acc[mt][nt][r];
                float e = __expf(2.f * s);
                out[(size_t)(m0 + row) * EO_ + n0 + col] = 1.f - 2.f / (e + 1.f);
            }
        }
    }
}

// ---- kernel 2: recurrence. 64 blocks x 4 waves, NO LDS, NO barriers. Wave (j,g) owns
// cols [16j,16j+16) of batch group g. W in 128 pinned VGPRs; A via 32 coherent 16B
// asm loads (128 VGPRs in flight, chunked vmcnt); swapped MFMA => per-lane contiguous I/O.
__launch_bounds__(256, 1)
__global__ void recur_kernel(const float* __restrict__ h0,
                             const unsigned short* __restrict__ whfT, // whf^T bf16 [N][K]
                             unsigned short* hbf,                     // [2][64][1024] bf16
                             unsigned int* flags,                     // [4][64]
                             float* out)
{
    const int j = blockIdx.x;            // col block 0..63
    const int tid = threadIdx.x;
    const int lane = tid & 63;
    const int g = tid >> 6;              // wave = batch group 0..3
    const int l15 = lane & 15, lg = lane >> 4;

    // W columns resident in registers for the whole kernel: 32 frags x 4 VGPR = 128, pinned.
    s16x8 Wf[32];
    #pragma unroll
    for (int kk = 0; kk < 32; ++kk)
        Wf[kk] = *(const s16x8*)(whfT + (size_t)(j * 16 + l15) * EO_ + kk * 32 + lg * 8);
    #pragma unroll
    for (int kk = 0; kk < 32; ++kk)
        asm volatile("" : "+v"(Wf[kk]));

    const int row = g * 16 + l15;         // batch row this lane produces (as MFMA D col)
    const int c0  = j * 16 + lg * 4;      // first of this lane's 4 output cols (D rows)
    float h[4];
    {
        f32x4 v = *(const f32x4*)(h0 + (size_t)row * EO_ + c0);
        h[0] = v[0]; h[1] = v[1]; h[2] = v[2]; h[3] = v[3];
    }
    unsigned int* const flg = flags + g * 64;

    for (int t = 0; t < T_; ++t) {
        // g_t prefetch (no cross-block dependence), issued before the poll
        f32x4 gv = *(const f32x4*)(out + ((size_t)row * T_ + t) * EO_ + c0);

        // poll: lane l watches producer block l of this group (t=0 passes trivially)
        const unsigned int want = (unsigned int)t;
        int spins = 0;
        for (;;) {
            unsigned int f = __hip_atomic_load(&flg[lane], __ATOMIC_RELAXED,
                                               __HIP_MEMORY_SCOPE_AGENT);
            if (__ballot(f >= want) == ~0ULL) break;
            if (++spins > (1 << 20)) break;          // safety valve
        }

        // drain prev-iter stores + gv so vmcnt chunk counts below are exact
        asm volatile("s_waitcnt vmcnt(0)" ::: "memory");
        __builtin_amdgcn_sched_barrier(0);

        // A = H_{t-1}[g], row l15, full K: 32 coherent 16B loads, ALL in flight.
        const char* aptr = (const char*)(hbf + (size_t)((t & 1) ^ 1) * 65536
                                         + (size_t)(g * 16 + l15) * 1024 + lg * 8);
        f32x4 ab[32];
#define CLD(OFF) asm volatile("global_load_dwordx4 %0, %1, off offset:" #OFF " sc0 sc1" \
                              : "=v"(ab[(OFF) / 64]) : "v"(aptr) : "memory")
        CLD(0);    CLD(64);   CLD(128);  CLD(192);  CLD(256);  CLD(320);  CLD(384);  CLD(448);
        CLD(512);  CLD(576);  CLD(640);  CLD(704);  CLD(768);  CLD(832);  CLD(896);  CLD(960);
        CLD(1024); CLD(1088); CLD(1152); CLD(1216); CLD(1280); CLD(1344); CLD(1408); CLD(1472);
        CLD(1536); CLD(1600); CLD(1664); CLD(1728); CLD(1792); CLD(1856); CLD(1920); CLD(1984);
#undef CLD

        f32x4 acc[4] = {};
        // chunk 0: wait oldest 8 loads, MFMA while the rest return
        asm volatile("s_waitcnt vmcnt(24)" ::: "memory");
        __builtin_amdgcn_sched_barrier(0);
        #pragma unroll
        for (int kk = 0; kk < 8; ++kk) {
            union { f32x4 f; s16x8 s; } a_; a_.f = ab[kk];
            acc[kk & 3] = __builtin_amdgcn_mfma_f32_16x16x32_bf16(Wf[kk], a_.s, acc[kk & 3], 0, 0, 0);
        }
        asm volatile("s_waitcnt vmcnt(16)" ::: "memory");
        __builtin_amdgcn_sched_barrier(0);
        #pragma unroll
        for (int kk = 8; kk < 16; ++kk) {
            union { f32x4 f; s16x8 s; } a_; a_.f = ab[kk];
            acc[kk & 3] = __builtin_amdgcn_mfma_f32_16x16x32_bf16(Wf[kk], a_.s, acc[kk & 3], 0, 0, 0);
        }
        asm volatile("s_waitcnt vmcnt(8)" ::: "memory");
        __builtin_amdgcn_sched_barrier(0);
        #pragma unroll
        for (int kk = 16; kk < 24; ++kk) {
            union { f32x4 f; s16x8 s; } a_; a_.f = ab[kk];
            acc[kk & 3] = __builtin_amdgcn_mfma_f32_16x16x32_bf16(Wf[kk], a_.s, acc[kk & 3], 0, 0, 0);
        }
        asm volatile("s_waitcnt vmcnt(0)" ::: "memory");
        __builtin_amdgcn_sched_barrier(0);
        #pragma unroll
        for (int kk = 24; kk < 32; ++kk) {
            union { f32x4 f; s16x8 s; } a_; a_.f = ab[kk];
            acc[kk & 3] = __builtin_amdgcn_mfma_f32_16x16x32_bf16(Wf[kk], a_.s, acc[kk & 3], 0, 0, 0);
        }

        // gate + state update (D: lane&15 = batch row col index n; regs = 4 contiguous cols)
        f32x4 ho;
        #pragma unroll
        for (int r = 0; r < 4; ++r) {
            float s = acc[0][r] + acc[1][r] + acc[2][r] + acc[3][r];
            float fg = 1.f / (1.f + __expf(-s));
            h[r] = (1.f - fg) * h[r] + fg * gv[r];
            ho[r] = h[r];
        }

        // critical path first: packed bf16 H-store -> drain -> flag. out-store afterwards.
        u64 pk = (u64)f2bf(h[0]) | ((u64)f2bf(h[1]) << 16)
               | ((u64)f2bf(h[2]) << 32) | ((u64)f2bf(h[3]) << 48);
        __hip_atomic_store((u64*)(hbf + (size_t)(t & 1) * 65536 + (size_t)row * 1024 + c0),
                           pk, __ATOMIC_RELAXED, __HIP_MEMORY_SCOPE_AGENT);
        asm volatile("s_waitcnt vmcnt(0)" ::: "memory");   // H-store drained before flag
        if (lane == 0)
            __hip_atomic_store(&flg[j], (unsigned int)(t + 1),
                               __ATOMIC_RELAXED, __HIP_MEMORY_SCOPE_AGENT);

        *(f32x4*)(out + ((size_t)row * T_ + t) * EO_ + c0) = ho;   // h_t -> outs (plain)
    }

    // final hidden state hT
    f32x4 hf; hf[0] = h[0]; hf[1] = h[1]; hf[2] = h[2]; hf[3] = h[3];
    *(f32x4*)(out + (size_t)B_ * T_ * EO_ + (size_t)row * EO_ + c0) = hf;
}

extern "C" void kernel_launch(void* const* d_in, const int* in_sizes, int n_in,
                              void* d_out, int out_size, void* d_ws, size_t ws_size,
                              hipStream_t stream)
{
    const float* x   = (const float*)d_in[0];
    const float* h0  = (const float*)d_in[1];
    const float* wxh = (const float*)d_in[2];
    const float* whf = (const float*)d_in[3];
    float* out = (float*)d_out;

    char* ws = (char*)d_ws;
    unsigned short* whfT  = (unsigned short*)(ws);                               // 2MB
    unsigned short* wxhT  = (unsigned short*)(ws + (size_t)2 * 1024 * 1024);     // 2MB
    unsigned short* hbf   = (unsigned short*)(ws + (size_t)4 * 1024 * 1024);     // 256KB
    unsigned int*   flags = (unsigned int*)  (ws + (size_t)4 * 1024 * 1024 + 256 * 1024);

    prep_kernel<<<512, 256, 0, stream>>>(wxh, whf, h0, wxhT, whfT, hbf, flags);
    gemm_g_kernel<<<2048, 256, 0, stream>>>(x, wxhT, out);
    recur_kernel<<<64, 256, 0, stream>>>(h0, whfT, hbf, flags, out);
}